// Round 9
// baseline (277.781 us; speedup 1.0000x reference)
//
#include <hip/hip_runtime.h>
#include <hip/hip_bf16.h>
#include <math.h>

#define HW   3136
#define NIMG 64
#define M_TOT (NIMG * HW)   // 200704

typedef __attribute__((ext_vector_type(8))) short bf16x8_t;
typedef __attribute__((ext_vector_type(4))) float f32x4_t;

__device__ __forceinline__ unsigned short f2bf(float f) {
  union { float f; unsigned u; } v; v.f = f;
  unsigned r = v.u + 0x7FFFu + ((v.u >> 16) & 1u);
  return (unsigned short)(r >> 16);
}
__device__ __forceinline__ float bf2f(unsigned short h) {
  union { unsigned u; float f; } v; v.u = ((unsigned)h) << 16;
  return v.f;
}

// ---------------- K0: swizzle weight [N][K] into MFMA B-fragment order ----
// frag fi = nt*(K/32)+kt ; element j of lane l <-> n = nt*16+(l&15),
// k = kt*32 + (l>>4)*8 + j.
__global__ void k0_swz(const float* __restrict__ wsrc, unsigned short* __restrict__ bsw,
                       int N, int K) {
  int idx = blockIdx.x * 256 + threadIdx.x;
  int total = (N / 16) * (K / 32) * 64;
  if (idx >= total) return;
  int l  = idx & 63;
  int fi = idx >> 6;
  int KT = K / 32;
  int nt = fi / KT, kt = fi - nt * KT;
  int nn = nt * 16 + (l & 15);
  int kb = kt * 32 + (l >> 4) * 8;
  const float* src = wsrc + (size_t)nn * K + kb;
  unsigned short* dst = bsw + (size_t)idx * 8;
#pragma unroll
  for (int j = 0; j < 8; j++) dst[j] = f2bf(src[j]);
}

// ---------------- K0c: fold GRN beta through w2 into bias ---------------
__global__ void k0_b2p(const float* __restrict__ w2, const float* __restrict__ grnb,
                       const float* __restrict__ b2, float* __restrict__ b2p) {
  int c = blockIdx.x * blockDim.x + threadIdx.x;
  if (c >= 96) return;
  float s = b2[c];
  const float* wr = w2 + (size_t)c * 384;
  for (int f = 0; f < 384; f++) s += grnb[f] * wr[f];
  b2p[c] = s;
}

// ---------------- K1a: depthwise 7x7 conv, direct-from-global -----------
// Phase 1: issue ALL 30 row-loads (pure loads, no dependent VALU).
// sched_barrier(0) fences the LLVM scheduler from sinking them (r8: without
// the fence the compiler interleaved load->use, VGPR 84, 96us latency-bound).
// Phase 2: zeroing + 784 FMAs from registers.
__global__ __launch_bounds__(256, 3) void k1a_dwconv(
    const float* __restrict__ x, const float* __restrict__ dww,
    const float* __restrict__ dwb, unsigned short* __restrict__ conv) {
  const int c = blockIdx.x, n = blockIdx.y;
  const int t = threadIdx.x;
  const int tx = t & 15, ty = t >> 4;   // tx 0..13 used, ty 0..13 used
  float wt[49];
#pragma unroll
  for (int j = 0; j < 49; j++) wt[j] = dww[c * 49 + j];   // uniform -> SGPR
  const float bias = dwb[c];
  const float* xp = x + ((size_t)n * 96 + c) * HW;

  const int b0 = tx * 4 - 4, b1 = tx * 4, b2c = tx * 4 + 4;
  const int col0 = min(max(b0, 0), 52);
  const int col1 = min(b1, 52);
  const int col2 = min(b2c, 52);
  const bool vok0 = (b0 >= 0) && (b0 <= 52);
  const bool vok1 = (b1 <= 52);
  const bool vok2 = (b2c <= 52);

  // ---- phase 1: 30 independent global_load_dwordx4, nothing else ----
  float4 raw[10][3];
#pragma unroll
  for (int rr = 0; rr < 10; rr++) {
    const int hr = ty * 4 + rr - 3;
    const bool rok = (unsigned)hr < 56u;
    const float* rp = xp + (rok ? hr : 0) * 56;
    raw[rr][0] = *(const float4*)(rp + col0);
    raw[rr][1] = *(const float4*)(rp + col1);
    raw[rr][2] = *(const float4*)(rp + col2);
  }
  __builtin_amdgcn_sched_barrier(0);   // loads stay above this line

  // ---- phase 2: zeroing + pure-register FMA reduction ----
  float acc[4][4];
#pragma unroll
  for (int py = 0; py < 4; py++)
#pragma unroll
    for (int px = 0; px < 4; px++) acc[py][px] = bias;
#pragma unroll
  for (int rr = 0; rr < 10; rr++) {
    const int hr = ty * 4 + rr - 3;
    const bool rok = (unsigned)hr < 56u;
    float4 v0 = raw[rr][0], v1 = raw[rr][1], v2 = raw[rr][2];
    if (!(rok && vok0)) v0 = make_float4(0.f, 0.f, 0.f, 0.f);
    if (!(rok && vok1)) v1 = make_float4(0.f, 0.f, 0.f, 0.f);
    if (!(rok && vok2)) v2 = make_float4(0.f, 0.f, 0.f, 0.f);
    float row[12];
    *(float4*)&row[0] = v0;
    *(float4*)&row[4] = v1;
    *(float4*)&row[8] = v2;
#pragma unroll
    for (int py = 0; py < 4; py++) {
      if (py <= rr && rr <= py + 6) {
        const int dy = rr - py;
#pragma unroll
        for (int px = 0; px < 4; px++)
#pragma unroll
          for (int dx = 0; dx < 7; dx++)
            acc[py][px] = fmaf(wt[dy * 7 + dx], row[px + dx + 1], acc[py][px]);
      }
    }
  }
  if (tx < 14 && ty < 14) {
    unsigned short* op = conv + ((size_t)n * 96 + c) * HW + (size_t)(ty * 4) * 56 + tx * 4;
#pragma unroll
    for (int py = 0; py < 4; py++) {
      ushort4 o;
      o.x = f2bf(acc[py][0]); o.y = f2bf(acc[py][1]);
      o.z = f2bf(acc[py][2]); o.w = f2bf(acc[py][3]);
      *(ushort4*)(op + (size_t)py * 56) = o;
    }
  }
}

// ------- K2f: transpose + LN + GEMM1 + GELU + gx2, y1 in FRAG-MAJOR -----
// Two half-feature passes through a small yt buffer (occupancy).
__global__ __launch_bounds__(256) void k2f_lngemm1(
    const unsigned short* __restrict__ conv, const float* __restrict__ lng,
    const float* __restrict__ lnb, const unsigned short* __restrict__ B1,
    const float* __restrict__ b1, unsigned short* __restrict__ y1f,
    float* __restrict__ gx2) {
  __shared__ unsigned short smbuf[64 * 200];   // 25.6 KB; ts (64x104) aliases yt (64x200)
  unsigned short (*ts)[104] = (unsigned short(*)[104])smbuf;
  unsigned short (*yt)[200] = (unsigned short(*)[200])smbuf;
  __shared__ float lnp[192];
  const int t = threadIdx.x;
  const int bid = blockIdx.x;
  const int n = bid / 49;
  const int hw0 = (bid - n * 49) * 64;
  if (t < 192) lnp[t] = (t < 96) ? lng[t] : lnb[t - 96];
  const unsigned short* cp0 = conv + (size_t)n * 96 * HW + hw0;
  for (int i = t; i < 96 * 32; i += 256) {
    int c = i >> 5, pxq = i & 31;
    unsigned u = *(const unsigned*)(cp0 + (size_t)c * HW + pxq * 2);
    ts[pxq * 2 + 0][c] = (unsigned short)(u & 0xffffu);
    ts[pxq * 2 + 1][c] = (unsigned short)(u >> 16);
  }
  __syncthreads();
  // ---- LayerNorm: 4 threads per pixel ----
  {
    const int px = t >> 2, q = t & 3;
    unsigned vu[12];
    float s = 0.f, ss = 0.f;
#pragma unroll
    for (int j = 0; j < 12; j++) {
      vu[j] = *(const unsigned*)&ts[px][q * 24 + j * 2];
      float v0 = bf2f((unsigned short)(vu[j] & 0xffffu));
      float v1 = bf2f((unsigned short)(vu[j] >> 16));
      s += v0 + v1; ss += v0 * v0 + v1 * v1;
    }
    s  += __shfl_xor(s, 1);  s  += __shfl_xor(s, 2);
    ss += __shfl_xor(ss, 1); ss += __shfl_xor(ss, 2);
    float mu  = s * (1.f / 96.f);
    float var = ss * (1.f / 96.f) - mu * mu;
    float rs  = rsqrtf(var + 1e-6f);
#pragma unroll
    for (int j = 0; j < 12; j++) {
      int ch = q * 24 + j * 2;
      float v0 = bf2f((unsigned short)(vu[j] & 0xffffu));
      float v1 = bf2f((unsigned short)(vu[j] >> 16));
      float o0 = (v0 - mu) * rs * lnp[ch] + lnp[96 + ch];
      float o1 = (v1 - mu) * rs * lnp[ch + 1] + lnp[96 + ch + 1];
      *(unsigned*)&ts[px][ch] = (unsigned)f2bf(o0) | ((unsigned)f2bf(o1) << 16);
    }
  }
  __syncthreads();
  // ---- A fragments from ts ----
  const int wv = t >> 6, l = t & 63;
  const int lg = l >> 4, lr = l & 15;
  bf16x8_t af[4][3];
#pragma unroll
  for (int mt = 0; mt < 4; mt++)
#pragma unroll
    for (int kt = 0; kt < 3; kt++)
      af[mt][kt] = *(const bf16x8_t*)&ts[mt * 16 + lr][kt * 32 + lg * 8];
  __syncthreads();   // ts reads drained before yt writes (aliased)

  // ---- GEMM1 + GELU(tanh-form) + gx2, two half-feature passes ----
  for (int half = 0; half < 2; half++) {
    for (int i = 0; i < 3; i++) {
      const int ntl = wv * 3 + i;          // 0..11 within half
      const int nt  = half * 12 + ntl;     // global 16-feature tile
      bf16x8_t bf[3];
#pragma unroll
      for (int kt = 0; kt < 3; kt++)
        bf[kt] = *(const bf16x8_t*)(B1 + ((size_t)(nt * 3 + kt) * 64 + l) * 8);
      f32x4_t acc[4];
#pragma unroll
      for (int mt = 0; mt < 4; mt++) {
        f32x4_t a = {0.f, 0.f, 0.f, 0.f};
#pragma unroll
        for (int kt = 0; kt < 3; kt++)
          a = __builtin_amdgcn_mfma_f32_16x16x32_bf16(af[mt][kt], bf[kt], a, 0, 0, 0);
        acc[mt] = a;
      }
      const int f0 = nt * 16, fl0 = ntl * 16;
      float bias = b1[f0 + lr];
      float s2 = 0.f;
#pragma unroll
      for (int mt = 0; mt < 4; mt++) {
#pragma unroll
        for (int r = 0; r < 4; r++) {
          float v = acc[mt][r] + bias;
          // exact-tanh GELU: g = v * sigmoid(1.5957691 v + 0.0713548 v^3)
          float sq = v * v;
          float pe = fmaf(sq, -0.0713548163f, -1.5957691216f);
          float e  = __expf(v * pe);
          float g  = v * __builtin_amdgcn_rcpf(1.f + e);
          s2 += g * g;
          yt[mt * 16 + lg * 4 + r][fl0 + lr] = f2bf(g);
        }
      }
      s2 += __shfl_xor(s2, 16);
      s2 += __shfl_xor(s2, 32);
      if (l < 16) atomicAdd(gx2 + n * 384 + f0 + l, s2);
    }
    __syncthreads();
    // frag-major readout of this half (kt = half*6 .. half*6+5)
#pragma unroll
    for (int it = 0; it < 6; it++) {
      int id = t + it * 256;               // 1536 = 4 mt * 6 ktl * 64 l
      int mt = id / 384, ktl = (id >> 6) % 6, ll = id & 63;
      uint4 d = *(const uint4*)&yt[mt * 16 + (ll & 15)][ktl * 32 + (ll >> 4) * 8];
      *(uint4*)(y1f + (((size_t)(bid * 4 + mt) * 12 + half * 6 + ktl) * 64 + ll) * 8) = d;
    }
    __syncthreads();
  }
}

// -------- K3: GRN coefficients + per-image scaled B2 fragments ----------
__global__ __launch_bounds__(256) void k3_coefB(
    const float* __restrict__ gx2, const float* __restrict__ grng,
    const unsigned short* __restrict__ B2, unsigned short* __restrict__ B2s) {
  __shared__ float red[256];
  __shared__ float cf[384];
  const int n = blockIdx.x, t = threadIdx.x;
  float s = 0.f;
  for (int f = t; f < 384; f += 256) {
    float g = sqrtf(gx2[n * 384 + f]);
    cf[f] = g; s += g;
  }
  red[t] = s; __syncthreads();
  for (int o = 128; o > 0; o >>= 1) {
    if (t < o) red[t] += red[t + o];
    __syncthreads();
  }
  float inv = 1.f / (red[0] * (1.f / 384.f) + 1e-6f);
  for (int f = t; f < 384; f += 256)
    cf[f] = 1.f + grng[f] * cf[f] * inv;
  __syncthreads();
  unsigned short* dstn = B2s + (size_t)n * 36864;
  for (int i = t; i < 4608; i += 256) {        // 4608 uint4 = 36864 elems
    int e0 = i * 8;
    int fi = e0 >> 9, ll = (e0 & 511) >> 3;
    int kb = (fi % 12) * 32 + (ll >> 4) * 8;
    uint4 w = *(const uint4*)(B2 + e0);
    const unsigned* wu = (const unsigned*)&w;
    uint4 o;
    unsigned* ou = (unsigned*)&o;
#pragma unroll
    for (int h = 0; h < 4; h++) {
      float v0 = bf2f((unsigned short)(wu[h] & 0xffffu)) * cf[kb + h * 2];
      float v1 = bf2f((unsigned short)(wu[h] >> 16)) * cf[kb + h * 2 + 1];
      ou[h] = (unsigned)f2bf(v0) | ((unsigned)f2bf(v1) << 16);
    }
    *(uint4*)(dstn + e0) = o;
  }
}

// ---------------- K4: GEMM2 (M x 96 x 384) + residual -------------------
__global__ __launch_bounds__(256) void k4_gemm2(
    const unsigned short* __restrict__ y1f, const unsigned short* __restrict__ B2s,
    const float* __restrict__ b2p, const float* __restrict__ x,
    float* __restrict__ out) {
  __shared__ float zt[96][68];
  const int t  = threadIdx.x;
  const int wv = t >> 6, l = t & 63;
  const int lg = l >> 4, lr = l & 15;
  const int m0 = blockIdx.x * 64;
  const int n  = m0 / HW, hw0 = m0 - n * HW;
  const unsigned short* Bn = B2s + (size_t)n * 36864;

  bf16x8_t af[12];
  const unsigned short* ap = y1f + ((size_t)(blockIdx.x * 4 + wv) * 12) * 512 + l * 8;
#pragma unroll
  for (int kt = 0; kt < 12; kt++)
    af[kt] = *(const bf16x8_t*)(ap + kt * 512);

  f32x4_t acc[6];
#pragma unroll
  for (int i = 0; i < 6; i++) acc[i] = (f32x4_t){0.f, 0.f, 0.f, 0.f};
#pragma unroll
  for (int kt = 0; kt < 12; kt++) {
#pragma unroll
    for (int nt = 0; nt < 6; nt++) {
      bf16x8_t b = *(const bf16x8_t*)(Bn + ((size_t)(nt * 12 + kt) * 64 + l) * 8);
      acc[nt] = __builtin_amdgcn_mfma_f32_16x16x32_bf16(af[kt], b, acc[nt], 0, 0, 0);
    }
  }
#pragma unroll
  for (int nt = 0; nt < 6; nt++) {
    int c = nt * 16 + lr;
#pragma unroll
    for (int r = 0; r < 4; r++)
      zt[c][wv * 16 + lg * 4 + r] = acc[nt][r];
  }
  __syncthreads();
#pragma unroll
  for (int it = 0; it < 6; it++) {
    int id = t + it * 256;  // 1536 = 96 c * 16 quads
    int c = id >> 4, mq = id & 15;
    float4 z = *(const float4*)&zt[c][mq * 4];
    size_t base = ((size_t)(n * 96 + c)) * HW + hw0 + mq * 4;
    float4 xv = *(const float4*)(x + base);
    float bp = b2p[c];
    float4 o;
    o.x = xv.x + z.x + bp;
    o.y = xv.y + z.y + bp;
    o.z = xv.z + z.z + bp;
    o.w = xv.w + z.w + bp;
    *(float4*)(out + base) = o;
  }
}

// ---------------- launch -----------------------------------------------
extern "C" void kernel_launch(void* const* d_in, const int* in_sizes, int n_in,
                              void* d_out, int out_size, void* d_ws, size_t ws_size,
                              hipStream_t stream) {
  const float* x    = (const float*)d_in[0];
  const float* dww  = (const float*)d_in[1];
  const float* dwb  = (const float*)d_in[2];
  const float* lng  = (const float*)d_in[3];
  const float* lnb  = (const float*)d_in[4];
  const float* w1   = (const float*)d_in[5];
  const float* b1   = (const float*)d_in[6];
  const float* grng = (const float*)d_in[7];
  const float* grnb = (const float*)d_in[8];
  const float* w2   = (const float*)d_in[9];
  const float* b2   = (const float*)d_in[10];
  float* out = (float*)d_out;

  char* ws = (char*)d_ws;
  size_t off = 0;
  auto alloc = [&](size_t bytes) {
    char* p = ws + off;
    off += (bytes + 255) & ~(size_t)255;
    return p;
  };
  unsigned short* y1f  = (unsigned short*)alloc((size_t)M_TOT * 384 * 2);
  unsigned short* convb = (unsigned short*)alloc((size_t)M_TOT * 96 * 2);
  unsigned short* B1sw = (unsigned short*)alloc((size_t)384 * 96 * 2);
  unsigned short* B2sw = (unsigned short*)alloc((size_t)96 * 384 * 2);
  float* gx2  = (float*)alloc((size_t)64 * 384 * 4);
  float* b2p  = (float*)alloc((size_t)96 * 4);
  if (off > ws_size) return;
  // B2s (per-image scaled w2 frags, 4.7 MB) aliases convb (dead after k2f).
  unsigned short* B2s = convb;

  hipMemsetAsync(gx2, 0, 64 * 384 * 4, stream);
  k0_swz<<<18, 256, 0, stream>>>(w1, B1sw, 384, 96);
  k0_swz<<<18, 256, 0, stream>>>(w2, B2sw, 96, 384);
  k0_b2p<<<1, 128, 0, stream>>>(w2, grnb, b2, b2p);
  k1a_dwconv<<<dim3(96, 64), 256, 0, stream>>>(x, dww, dwb, convb);
  k2f_lngemm1<<<3136, 256, 0, stream>>>(convb, lng, lnb, B1sw, b1, y1f, gx2);
  k3_coefB<<<64, 256, 0, stream>>>(gx2, grng, B2sw, B2s);
  k4_gemm2<<<3136, 256, 0, stream>>>(y1f, B2s, b2p, x, out);
}

// Round 11
// 272.112 us; speedup vs baseline: 1.0208x; 1.0208x over previous
//
#include <hip/hip_runtime.h>
#include <hip/hip_bf16.h>
#include <math.h>

#define HW   3136
#define NIMG 64
#define M_TOT (NIMG * HW)   // 200704

typedef __attribute__((ext_vector_type(8))) short bf16x8_t;
typedef __attribute__((ext_vector_type(4))) float f32x4_t;

__device__ __forceinline__ unsigned short f2bf(float f) {
  union { float f; unsigned u; } v; v.f = f;
  unsigned r = v.u + 0x7FFFu + ((v.u >> 16) & 1u);
  return (unsigned short)(r >> 16);
}
__device__ __forceinline__ float bf2f(unsigned short h) {
  union { unsigned u; float f; } v; v.u = ((unsigned)h) << 16;
  return v.f;
}

// ---------------- K0: swizzle weight [N][K] into MFMA B-fragment order ----
__global__ void k0_swz(const float* __restrict__ wsrc, unsigned short* __restrict__ bsw,
                       int N, int K) {
  int idx = blockIdx.x * 256 + threadIdx.x;
  int total = (N / 16) * (K / 32) * 64;
  if (idx >= total) return;
  int l  = idx & 63;
  int fi = idx >> 6;
  int KT = K / 32;
  int nt = fi / KT, kt = fi - nt * KT;
  int nn = nt * 16 + (l & 15);
  int kb = kt * 32 + (l >> 4) * 8;
  const float* src = wsrc + (size_t)nn * K + kb;
  unsigned short* dst = bsw + (size_t)idx * 8;
#pragma unroll
  for (int j = 0; j < 8; j++) dst[j] = f2bf(src[j]);
}

// ---------------- K0c: fold GRN beta through w2 into bias ---------------
__global__ void k0_b2p(const float* __restrict__ w2, const float* __restrict__ grnb,
                       const float* __restrict__ b2, float* __restrict__ b2p) {
  int c = blockIdx.x * blockDim.x + threadIdx.x;
  if (c >= 96) return;
  float s = b2[c];
  const float* wr = w2 + (size_t)c * 384;
  for (int f = 0; f < 384; f++) s += grnb[f] * wr[f];
  b2p[c] = s;
}

// ---------------- K0w: dwconv weights -> bf16, rows padded to 8 ---------
__global__ void k0w(const float* __restrict__ dww, unsigned short* __restrict__ wswz) {
  int i = blockIdx.x * 256 + threadIdx.x;   // over 96*56
  if (i >= 96 * 56) return;
  int ch = i / 56, rem = i - ch * 56, dy = rem >> 3, dx = rem & 7;
  wswz[i] = (dx < 7) ? f2bf(dww[ch * 49 + dy * 7 + dx]) : (unsigned short)0;
}

// ===== K12f: FUSED dwconv + transpose + LN + GEMM1 + GELU + gx2 =========
// Block = one 8x8 pixel tile of one image (grid 64*49). 256 threads.
// Conv: 3 chunks of 32 ch; xsh halo staged bf16; thread = 1 row x 8 cols of
// one channel (all-static indexing); ts/yt alias xsh region after conv.
__global__ __launch_bounds__(256, 3) void k12f(
    const float* __restrict__ x, const unsigned short* __restrict__ wswz,
    const float* __restrict__ dwb, const float* __restrict__ lng,
    const float* __restrict__ lnb, const unsigned short* __restrict__ B1,
    const float* __restrict__ b1, unsigned short* __restrict__ y1f,
    float* __restrict__ gx2) {
  __shared__ char smem[39680];
  unsigned short* wsw = (unsigned short*)smem;                  // [96][7][8] bf16, 10752 B
  float* lnp = (float*)(smem + 10752);                          // 192 f32, 768 B
  unsigned short* xsh = (unsigned short*)(smem + 11520);        // [32] ch-stride 232, 14848 B
  unsigned short (*ts)[104] = (unsigned short(*)[104])(smem + 26368);  // 13312 B
  unsigned short (*yt)[200] = (unsigned short(*)[200])(smem + 11520);  // aliases xsh+ts

  const int t = threadIdx.x;
  const int bid = blockIdx.x;
  const int n = bid / 49;
  const int tile = bid - n * 49;
  const int tr = tile / 7, tc = tile - tr * 7;
  const int h0 = tr * 8, w0 = tc * 8;

  // stage weights (10752 B = 672 uint4) + ln params
#pragma unroll
  for (int k = 0; k < 3; k++) {
    int i = t + k * 256;
    if (i < 672) ((uint4*)wsw)[i] = ((const uint4*)wswz)[i];
  }
  if (t < 192) lnp[t] = (t < 96) ? lng[t] : lnb[t - 96];

  // ---- conv: 3 chunks of 32 channels ----
  const int cch = t & 31, crow = t >> 5;       // conv mapping: channel, out-row
  for (int cc = 0; cc < 3; cc++) {
    const int c0 = cc * 32;
    if (cc) __syncthreads();     // prior chunk's conv reads done
    // stage xsh[ch][14][16] bf16 (halo, zero-padded); 1792 b64 writes
#pragma unroll
    for (int k = 0; k < 7; k++) {
      int i = t + k * 256;                 // < 1792
      int cq = i & 3;
      int rc = i >> 2;                     // 0..447
      int r = rc % 14, ch = rc / 14;
      int h = h0 + r - 3;
      const float* xb = x + (size_t)(n * 96 + c0 + ch) * HW + h * 56;
      bool hok = (unsigned)h < 56u;
      int wb = w0 + cq * 4 - 3;
      float a0 = (hok && (unsigned)(wb + 0) < 56u) ? xb[wb + 0] : 0.f;
      float a1 = (hok && (unsigned)(wb + 1) < 56u) ? xb[wb + 1] : 0.f;
      float a2 = (hok && (unsigned)(wb + 2) < 56u) ? xb[wb + 2] : 0.f;
      float a3 = (hok && (unsigned)(wb + 3) < 56u) ? xb[wb + 3] : 0.f;
      uint2 u;
      u.x = (unsigned)f2bf(a0) | ((unsigned)f2bf(a1) << 16);
      u.y = (unsigned)f2bf(a2) | ((unsigned)f2bf(a3) << 16);
      *(uint2*)&xsh[ch * 232 + r * 16 + cq * 4] = u;
    }
    __syncthreads();
    // conv compute: thread = 8 outputs (row crow, cols 0..7) of ch c0+cch
    float wf[7][7];
#pragma unroll
    for (int dy = 0; dy < 7; dy++) {
      bf16x8_t wv8 = *(const bf16x8_t*)&wsw[(c0 + cch) * 56 + dy * 8];  // FIX r10: was cch*56
#pragma unroll
      for (int dx = 0; dx < 7; dx++) wf[dy][dx] = bf2f((unsigned short)wv8[dx]);
    }
    const float bias = dwb[c0 + cch];
    float acc[8];
#pragma unroll
    for (int j = 0; j < 8; j++) acc[j] = bias;
#pragma unroll
    for (int dy = 0; dy < 7; dy++) {
      const unsigned short* xr = &xsh[cch * 232 + (crow + dy) * 16];
      bf16x8_t x0 = *(const bf16x8_t*)xr;
      bf16x8_t x1 = *(const bf16x8_t*)(xr + 8);
      float r16[14];
#pragma unroll
      for (int k = 0; k < 8; k++) r16[k] = bf2f((unsigned short)x0[k]);
#pragma unroll
      for (int k = 0; k < 6; k++) r16[8 + k] = bf2f((unsigned short)x1[k]);
#pragma unroll
      for (int j = 0; j < 8; j++)
#pragma unroll
        for (int dx = 0; dx < 7; dx++)
          acc[j] = fmaf(wf[dy][dx], r16[j + dx], acc[j]);
    }
#pragma unroll
    for (int j = 0; j < 8; j++)
      ts[crow * 8 + j][c0 + cch] = f2bf(acc[j]);
  }
  __syncthreads();

  // ---- LayerNorm: 4 threads per pixel (px = tile-local 0..63) ----
  {
    const int px = t >> 2, q = t & 3;
    unsigned vu[12];
    float s = 0.f, ss = 0.f;
#pragma unroll
    for (int j = 0; j < 12; j++) {
      vu[j] = *(const unsigned*)&ts[px][q * 24 + j * 2];
      float v0 = bf2f((unsigned short)(vu[j] & 0xffffu));
      float v1 = bf2f((unsigned short)(vu[j] >> 16));
      s += v0 + v1; ss += v0 * v0 + v1 * v1;
    }
    s  += __shfl_xor(s, 1);  s  += __shfl_xor(s, 2);
    ss += __shfl_xor(ss, 1); ss += __shfl_xor(ss, 2);
    float mu  = s * (1.f / 96.f);
    float var = ss * (1.f / 96.f) - mu * mu;
    float rs  = rsqrtf(var + 1e-6f);
#pragma unroll
    for (int j = 0; j < 12; j++) {
      int ch = q * 24 + j * 2;
      float v0 = bf2f((unsigned short)(vu[j] & 0xffffu));
      float v1 = bf2f((unsigned short)(vu[j] >> 16));
      float o0 = (v0 - mu) * rs * lnp[ch] + lnp[96 + ch];
      float o1 = (v1 - mu) * rs * lnp[ch + 1] + lnp[96 + ch + 1];
      *(unsigned*)&ts[px][ch] = (unsigned)f2bf(o0) | ((unsigned)f2bf(o1) << 16);
    }
  }
  __syncthreads();
  // ---- A fragments from ts ----
  const int wv = t >> 6, l = t & 63;
  const int lg = l >> 4, lr = l & 15;
  bf16x8_t af[4][3];
#pragma unroll
  for (int mt = 0; mt < 4; mt++)
#pragma unroll
    for (int kt = 0; kt < 3; kt++)
      af[mt][kt] = *(const bf16x8_t*)&ts[mt * 16 + lr][kt * 32 + lg * 8];
  __syncthreads();   // ts dies; yt (aliased) may be written

  // ---- GEMM1 + GELU(tanh-form) + gx2, two half-feature passes ----
  for (int half = 0; half < 2; half++) {
    for (int i = 0; i < 3; i++) {
      const int ntl = wv * 3 + i;
      const int nt  = half * 12 + ntl;
      bf16x8_t bf[3];
#pragma unroll
      for (int kt = 0; kt < 3; kt++)
        bf[kt] = *(const bf16x8_t*)(B1 + ((size_t)(nt * 3 + kt) * 64 + l) * 8);
      f32x4_t acc[4];
#pragma unroll
      for (int mt = 0; mt < 4; mt++) {
        f32x4_t a = {0.f, 0.f, 0.f, 0.f};
#pragma unroll
        for (int kt = 0; kt < 3; kt++)
          a = __builtin_amdgcn_mfma_f32_16x16x32_bf16(af[mt][kt], bf[kt], a, 0, 0, 0);
        acc[mt] = a;
      }
      const int f0 = nt * 16, fl0 = ntl * 16;
      float bias = b1[f0 + lr];
      float s2 = 0.f;
#pragma unroll
      for (int mt = 0; mt < 4; mt++) {
#pragma unroll
        for (int r = 0; r < 4; r++) {
          float v = acc[mt][r] + bias;
          float sq = v * v;
          float pe = fmaf(sq, -0.0713548163f, -1.5957691216f);
          float e  = __expf(v * pe);
          float g  = v * __builtin_amdgcn_rcpf(1.f + e);
          s2 += g * g;
          yt[mt * 16 + lg * 4 + r][fl0 + lr] = f2bf(g);
        }
      }
      s2 += __shfl_xor(s2, 16);
      s2 += __shfl_xor(s2, 32);
      if (l < 16) atomicAdd(gx2 + n * 384 + f0 + l, s2);
    }
    __syncthreads();
#pragma unroll
    for (int it = 0; it < 6; it++) {
      int id = t + it * 256;
      int mt = id / 384, ktl = (id >> 6) % 6, ll = id & 63;
      uint4 d = *(const uint4*)&yt[mt * 16 + (ll & 15)][ktl * 32 + (ll >> 4) * 8];
      *(uint4*)(y1f + (((size_t)(bid * 4 + mt) * 12 + half * 6 + ktl) * 64 + ll) * 8) = d;
    }
    __syncthreads();
  }
}

// -------- K3: GRN coefficients + per-image scaled B2 fragments ----------
__global__ __launch_bounds__(256) void k3_coefB(
    const float* __restrict__ gx2, const float* __restrict__ grng,
    const unsigned short* __restrict__ B2, unsigned short* __restrict__ B2s) {
  __shared__ float red[256];
  __shared__ float cf[384];
  const int n = blockIdx.x, t = threadIdx.x;
  float s = 0.f;
  for (int f = t; f < 384; f += 256) {
    float g = sqrtf(gx2[n * 384 + f]);
    cf[f] = g; s += g;
  }
  red[t] = s; __syncthreads();
  for (int o = 128; o > 0; o >>= 1) {
    if (t < o) red[t] += red[t + o];
    __syncthreads();
  }
  float inv = 1.f / (red[0] * (1.f / 384.f) + 1e-6f);
  for (int f = t; f < 384; f += 256)
    cf[f] = 1.f + grng[f] * cf[f] * inv;
  __syncthreads();
  unsigned short* dstn = B2s + (size_t)n * 36864;
  for (int i = t; i < 4608; i += 256) {
    int e0 = i * 8;
    int fi = e0 >> 9, ll = (e0 & 511) >> 3;
    int kb = (fi % 12) * 32 + (ll >> 4) * 8;
    uint4 w = *(const uint4*)(B2 + e0);
    const unsigned* wu = (const unsigned*)&w;
    uint4 o;
    unsigned* ou = (unsigned*)&o;
#pragma unroll
    for (int h = 0; h < 4; h++) {
      float v0 = bf2f((unsigned short)(wu[h] & 0xffffu)) * cf[kb + h * 2];
      float v1 = bf2f((unsigned short)(wu[h] >> 16)) * cf[kb + h * 2 + 1];
      ou[h] = (unsigned)f2bf(v0) | ((unsigned)f2bf(v1) << 16);
    }
    *(uint4*)(dstn + e0) = o;
  }
}

// ---------------- K4: GEMM2 (M x 96 x 384) + residual -------------------
// M-tiles are 8x8 spatial tiles (matching k12f); epilogue remaps.
__global__ __launch_bounds__(256) void k4_gemm2(
    const unsigned short* __restrict__ y1f, const unsigned short* __restrict__ B2s,
    const float* __restrict__ b2p, const float* __restrict__ x,
    float* __restrict__ out) {
  __shared__ float zt[96][68];
  const int t  = threadIdx.x;
  const int wv = t >> 6, l = t & 63;
  const int lg = l >> 4, lr = l & 15;
  const int bid = blockIdx.x;
  const int n = bid / 49;
  const int tile = bid - n * 49;
  const int tr = tile / 7, tc = tile - tr * 7;
  const unsigned short* Bn = B2s + (size_t)n * 36864;

  bf16x8_t af[12];
  const unsigned short* ap = y1f + ((size_t)(bid * 4 + wv) * 12) * 512 + l * 8;
#pragma unroll
  for (int kt = 0; kt < 12; kt++)
    af[kt] = *(const bf16x8_t*)(ap + kt * 512);

  f32x4_t acc[6];
#pragma unroll
  for (int i = 0; i < 6; i++) acc[i] = (f32x4_t){0.f, 0.f, 0.f, 0.f};
#pragma unroll
  for (int kt = 0; kt < 12; kt++) {
#pragma unroll
    for (int nt = 0; nt < 6; nt++) {
      bf16x8_t b = *(const bf16x8_t*)(Bn + ((size_t)(nt * 12 + kt) * 64 + l) * 8);
      acc[nt] = __builtin_amdgcn_mfma_f32_16x16x32_bf16(af[kt], b, acc[nt], 0, 0, 0);
    }
  }
#pragma unroll
  for (int nt = 0; nt < 6; nt++) {
    int c = nt * 16 + lr;
#pragma unroll
    for (int r = 0; r < 4; r++)
      zt[c][wv * 16 + lg * 4 + r] = acc[nt][r];
  }
  __syncthreads();
#pragma unroll
  for (int it = 0; it < 6; it++) {
    int id = t + it * 256;  // 1536 = 96 c * 16 quads
    int c = id >> 4, q = id & 15;
    int row = q >> 1, jq = (q & 1) * 4;     // m-local = q*4 .. q*4+3
    float4 z = *(const float4*)&zt[c][row * 8 + jq];
    size_t base = ((size_t)(n * 96 + c)) * HW + (size_t)(tr * 8 + row) * 56 + tc * 8 + jq;
    float4 xv = *(const float4*)(x + base);
    float bp = b2p[c];
    float4 o;
    o.x = xv.x + z.x + bp;
    o.y = xv.y + z.y + bp;
    o.z = xv.z + z.z + bp;
    o.w = xv.w + z.w + bp;
    *(float4*)(out + base) = o;
  }
}

// ---------------- launch -----------------------------------------------
extern "C" void kernel_launch(void* const* d_in, const int* in_sizes, int n_in,
                              void* d_out, int out_size, void* d_ws, size_t ws_size,
                              hipStream_t stream) {
  const float* x    = (const float*)d_in[0];
  const float* dww  = (const float*)d_in[1];
  const float* dwb  = (const float*)d_in[2];
  const float* lng  = (const float*)d_in[3];
  const float* lnb  = (const float*)d_in[4];
  const float* w1   = (const float*)d_in[5];
  const float* b1   = (const float*)d_in[6];
  const float* grng = (const float*)d_in[7];
  const float* grnb = (const float*)d_in[8];
  const float* w2   = (const float*)d_in[9];
  const float* b2   = (const float*)d_in[10];
  float* out = (float*)d_out;

  char* ws = (char*)d_ws;
  size_t off = 0;
  auto alloc = [&](size_t bytes) {
    char* p = ws + off;
    off += (bytes + 255) & ~(size_t)255;
    return p;
  };
  unsigned short* y1f  = (unsigned short*)alloc((size_t)M_TOT * 384 * 2);
  unsigned short* B2s  = (unsigned short*)alloc((size_t)64 * 36864 * 2);
  unsigned short* B1sw = (unsigned short*)alloc((size_t)384 * 96 * 2);
  unsigned short* B2sw = (unsigned short*)alloc((size_t)96 * 384 * 2);
  unsigned short* wswz = (unsigned short*)alloc((size_t)96 * 56 * 2);
  float* gx2  = (float*)alloc((size_t)64 * 384 * 4);
  float* b2p  = (float*)alloc((size_t)96 * 4);
  if (off > ws_size) return;

  hipMemsetAsync(gx2, 0, 64 * 384 * 4, stream);
  k0_swz<<<18, 256, 0, stream>>>(w1, B1sw, 384, 96);
  k0_swz<<<18, 256, 0, stream>>>(w2, B2sw, 96, 384);
  k0_b2p<<<1, 128, 0, stream>>>(w2, grnb, b2, b2p);
  k0w<<<21, 256, 0, stream>>>(dww, wswz);
  k12f<<<3136, 256, 0, stream>>>(x, wswz, dwb, lng, lnb, B1sw, b1, y1f, gx2);
  k3_coefB<<<64, 256, 0, stream>>>(gx2, grng, B2sw, B2s);
  k4_gemm2<<<3136, 256, 0, stream>>>(y1f, B2s, b2p, x, out);
}

// Round 12
// 269.418 us; speedup vs baseline: 1.0310x; 1.0100x over previous
//
#include <hip/hip_runtime.h>
#include <hip/hip_bf16.h>
#include <math.h>

#define HW   3136
#define NIMG 64
#define M_TOT (NIMG * HW)   // 200704

typedef __attribute__((ext_vector_type(8))) short bf16x8_t;
typedef __attribute__((ext_vector_type(4))) float f32x4_t;

__device__ __forceinline__ unsigned short f2bf(float f) {
  union { float f; unsigned u; } v; v.f = f;
  unsigned r = v.u + 0x7FFFu + ((v.u >> 16) & 1u);
  return (unsigned short)(r >> 16);
}
__device__ __forceinline__ float bf2f(unsigned short h) {
  union { unsigned u; float f; } v; v.u = ((unsigned)h) << 16;
  return v.f;
}

// ---------------- K0: swizzle weight [N][K] into MFMA B-fragment order ----
__global__ void k0_swz(const float* __restrict__ wsrc, unsigned short* __restrict__ bsw,
                       int N, int K) {
  int idx = blockIdx.x * 256 + threadIdx.x;
  int total = (N / 16) * (K / 32) * 64;
  if (idx >= total) return;
  int l  = idx & 63;
  int fi = idx >> 6;
  int KT = K / 32;
  int nt = fi / KT, kt = fi - nt * KT;
  int nn = nt * 16 + (l & 15);
  int kb = kt * 32 + (l >> 4) * 8;
  const float* src = wsrc + (size_t)nn * K + kb;
  unsigned short* dst = bsw + (size_t)idx * 8;
#pragma unroll
  for (int j = 0; j < 8; j++) dst[j] = f2bf(src[j]);
}

// ---------------- K0c: fold GRN beta through w2 into bias ---------------
__global__ void k0_b2p(const float* __restrict__ w2, const float* __restrict__ grnb,
                       const float* __restrict__ b2, float* __restrict__ b2p) {
  int c = blockIdx.x * blockDim.x + threadIdx.x;
  if (c >= 96) return;
  float s = b2[c];
  const float* wr = w2 + (size_t)c * 384;
  for (int f = 0; f < 384; f++) s += grnb[f] * wr[f];
  b2p[c] = s;
}

// ---------------- K0w: dwconv weights -> bf16, rows padded to 8 ---------
__global__ void k0w(const float* __restrict__ dww, unsigned short* __restrict__ wswz) {
  int i = blockIdx.x * 256 + threadIdx.x;   // over 96*56
  if (i >= 96 * 56) return;
  int ch = i / 56, rem = i - ch * 56, dy = rem >> 3, dx = rem & 7;
  wswz[i] = (dx < 7) ? f2bf(dww[ch * 49 + dy * 7 + dx]) : (unsigned short)0;
}

// ===== K12f: FUSED dwconv + transpose + LN + GEMM1 + GELU + gx2 =========
// Block = one 8x8 pixel tile of one image (grid 64*49). 256 threads.
// r12: weights from global (no wsw LDS, 39.7->28.9 KB -> 5 blocks/CU);
// interior-tile float4 staging fast path; GELU exp2-folded.
__global__ __launch_bounds__(256, 3) void k12f(
    const float* __restrict__ x, const unsigned short* __restrict__ wswz,
    const float* __restrict__ dwb, const float* __restrict__ lng,
    const float* __restrict__ lnb, const unsigned short* __restrict__ B1,
    const float* __restrict__ b1, unsigned short* __restrict__ y1f,
    float* __restrict__ gx2) {
  __shared__ char smem[28928];
  float* lnp = (float*)smem;                                    // 768 B
  unsigned short* xsh = (unsigned short*)(smem + 768);          // [32] ch-stride 232 us (464 B), 14848 B
  unsigned short (*ts)[104] = (unsigned short(*)[104])(smem + 15616);  // 13312 B
  unsigned short (*yt)[200] = (unsigned short(*)[200])(smem + 768);    // aliases xsh+ts (25600 B)

  const int t = threadIdx.x;
  const int bid = blockIdx.x;
  const int n = bid / 49;
  const int tile = bid - n * 49;
  const int tr = tile / 7, tc = tile - tr * 7;
  const int h0 = tr * 8, w0 = tc * 8;

  if (t < 192) lnp[t] = (t < 96) ? lng[t] : lnb[t - 96];

  // ---- conv: 3 chunks of 32 channels ----
  const int cch = t & 31, crow = t >> 5;       // conv mapping: channel, out-row
  const bool colInt = (tc >= 1) && (tc <= 5);  // all 16 staged cols in-bounds
  for (int cc = 0; cc < 3; cc++) {
    const int c0 = cc * 32;
    if (cc) __syncthreads();     // prior chunk's conv reads done
    // stage xsh[ch][14][16] bf16 (halo, zero-padded); 1792 uint2 writes
#pragma unroll
    for (int k = 0; k < 7; k++) {
      int i = t + k * 256;                 // < 1792
      int cq = i & 3;
      int rc = i >> 2;                     // 0..447
      int r = rc % 14, ch = rc / 14;
      int h = h0 + r - 3;
      int wb = w0 + cq * 4 - 3;
      const float* xb = x + (size_t)(n * 96 + c0 + ch) * HW + h * 56 + wb;
      float4 v = make_float4(0.f, 0.f, 0.f, 0.f);
      if ((unsigned)h < 56u) {
        if (colInt) {
          v = *(const float4*)xb;          // 4B-aligned; HW allows unaligned global vec
        } else {
          if ((unsigned)(wb + 0) < 56u) v.x = xb[0];
          if ((unsigned)(wb + 1) < 56u) v.y = xb[1];
          if ((unsigned)(wb + 2) < 56u) v.z = xb[2];
          if ((unsigned)(wb + 3) < 56u) v.w = xb[3];
        }
      }
      uint2 u;
      u.x = (unsigned)f2bf(v.x) | ((unsigned)f2bf(v.y) << 16);
      u.y = (unsigned)f2bf(v.z) | ((unsigned)f2bf(v.w) << 16);
      *(uint2*)&xsh[ch * 232 + r * 16 + cq * 4] = u;
    }
    // per-channel weights straight from global (L2-hot 10.5 KB), packed regs;
    // issued before the barrier so latency hides under staging drain.
    bf16x8_t wv[7];
#pragma unroll
    for (int dy = 0; dy < 7; dy++)
      wv[dy] = *(const bf16x8_t*)&wswz[(size_t)(c0 + cch) * 56 + dy * 8];
    const float bias = dwb[c0 + cch];
    __syncthreads();
    // conv compute: thread = 8 outputs (row crow, cols 0..7) of ch c0+cch
    float acc[8];
#pragma unroll
    for (int j = 0; j < 8; j++) acc[j] = bias;
#pragma unroll
    for (int dy = 0; dy < 7; dy++) {
      float wf[7];
#pragma unroll
      for (int dx = 0; dx < 7; dx++) wf[dx] = bf2f((unsigned short)wv[dy][dx]);
      const unsigned short* xr = &xsh[cch * 232 + (crow + dy) * 16];
      bf16x8_t x0 = *(const bf16x8_t*)xr;
      bf16x8_t x1 = *(const bf16x8_t*)(xr + 8);
      float r16[14];
#pragma unroll
      for (int k = 0; k < 8; k++) r16[k] = bf2f((unsigned short)x0[k]);
#pragma unroll
      for (int k = 0; k < 6; k++) r16[8 + k] = bf2f((unsigned short)x1[k]);
#pragma unroll
      for (int j = 0; j < 8; j++)
#pragma unroll
        for (int dx = 0; dx < 7; dx++)
          acc[j] = fmaf(wf[dx], r16[j + dx], acc[j]);
    }
#pragma unroll
    for (int j = 0; j < 8; j++)
      ts[crow * 8 + j][c0 + cch] = f2bf(acc[j]);
  }
  __syncthreads();

  // ---- LayerNorm: 4 threads per pixel (px = tile-local 0..63) ----
  {
    const int px = t >> 2, q = t & 3;
    unsigned vu[12];
    float s = 0.f, ss = 0.f;
#pragma unroll
    for (int j = 0; j < 12; j++) {
      vu[j] = *(const unsigned*)&ts[px][q * 24 + j * 2];
      float v0 = bf2f((unsigned short)(vu[j] & 0xffffu));
      float v1 = bf2f((unsigned short)(vu[j] >> 16));
      s += v0 + v1; ss += v0 * v0 + v1 * v1;
    }
    s  += __shfl_xor(s, 1);  s  += __shfl_xor(s, 2);
    ss += __shfl_xor(ss, 1); ss += __shfl_xor(ss, 2);
    float mu  = s * (1.f / 96.f);
    float var = ss * (1.f / 96.f) - mu * mu;
    float rs  = rsqrtf(var + 1e-6f);
#pragma unroll
    for (int j = 0; j < 12; j++) {
      int ch = q * 24 + j * 2;
      float v0 = bf2f((unsigned short)(vu[j] & 0xffffu));
      float v1 = bf2f((unsigned short)(vu[j] >> 16));
      float o0 = (v0 - mu) * rs * lnp[ch] + lnp[96 + ch];
      float o1 = (v1 - mu) * rs * lnp[ch + 1] + lnp[96 + ch + 1];
      *(unsigned*)&ts[px][ch] = (unsigned)f2bf(o0) | ((unsigned)f2bf(o1) << 16);
    }
  }
  __syncthreads();
  // ---- A fragments from ts ----
  const int wv_ = t >> 6, l = t & 63;
  const int lg = l >> 4, lr = l & 15;
  bf16x8_t af[4][3];
#pragma unroll
  for (int mt = 0; mt < 4; mt++)
#pragma unroll
    for (int kt = 0; kt < 3; kt++)
      af[mt][kt] = *(const bf16x8_t*)&ts[mt * 16 + lr][kt * 32 + lg * 8];
  __syncthreads();   // ts dies; yt (aliased) may be written

  // ---- GEMM1 + GELU + gx2, two half-feature passes ----
  for (int half = 0; half < 2; half++) {
    for (int i = 0; i < 3; i++) {
      const int ntl = wv_ * 3 + i;
      const int nt  = half * 12 + ntl;
      bf16x8_t bf[3];
#pragma unroll
      for (int kt = 0; kt < 3; kt++)
        bf[kt] = *(const bf16x8_t*)(B1 + ((size_t)(nt * 3 + kt) * 64 + l) * 8);
      f32x4_t acc[4];
#pragma unroll
      for (int mt = 0; mt < 4; mt++) {
        f32x4_t a = {0.f, 0.f, 0.f, 0.f};
#pragma unroll
        for (int kt = 0; kt < 3; kt++)
          a = __builtin_amdgcn_mfma_f32_16x16x32_bf16(af[mt][kt], bf[kt], a, 0, 0, 0);
        acc[mt] = a;
      }
      const int f0 = nt * 16, fl0 = ntl * 16;
      float bias = b1[f0 + lr];
      float s2 = 0.f;
#pragma unroll
      for (int mt = 0; mt < 4; mt++) {
#pragma unroll
        for (int r = 0; r < 4; r++) {
          float v = acc[mt][r] + bias;
          // g = v * sigmoid(1.5957691 v + 0.0713548 v^3), exp2-folded
          float sq = v * v;
          float pe = fmaf(sq, -0.10295294f, -2.3021183f);   // consts * log2(e)
          float e  = __builtin_amdgcn_exp2f(v * pe);
          float g  = v * __builtin_amdgcn_rcpf(1.f + e);
          s2 += g * g;
          yt[mt * 16 + lg * 4 + r][fl0 + lr] = f2bf(g);
        }
      }
      s2 += __shfl_xor(s2, 16);
      s2 += __shfl_xor(s2, 32);
      if (l < 16) atomicAdd(gx2 + n * 384 + f0 + l, s2);
    }
    __syncthreads();
#pragma unroll
    for (int it = 0; it < 6; it++) {
      int id = t + it * 256;
      int mt = id / 384, ktl = (id >> 6) % 6, ll = id & 63;
      uint4 d = *(const uint4*)&yt[mt * 16 + (ll & 15)][ktl * 32 + (ll >> 4) * 8];
      *(uint4*)(y1f + (((size_t)(bid * 4 + mt) * 12 + half * 6 + ktl) * 64 + ll) * 8) = d;
    }
    __syncthreads();
  }
}

// -------- K3: GRN coefficients + per-image scaled B2 fragments ----------
__global__ __launch_bounds__(256) void k3_coefB(
    const float* __restrict__ gx2, const float* __restrict__ grng,
    const unsigned short* __restrict__ B2, unsigned short* __restrict__ B2s) {
  __shared__ float red[256];
  __shared__ float cf[384];
  const int n = blockIdx.x, t = threadIdx.x;
  float s = 0.f;
  for (int f = t; f < 384; f += 256) {
    float g = sqrtf(gx2[n * 384 + f]);
    cf[f] = g; s += g;
  }
  red[t] = s; __syncthreads();
  for (int o = 128; o > 0; o >>= 1) {
    if (t < o) red[t] += red[t + o];
    __syncthreads();
  }
  float inv = 1.f / (red[0] * (1.f / 384.f) + 1e-6f);
  for (int f = t; f < 384; f += 256)
    cf[f] = 1.f + grng[f] * cf[f] * inv;
  __syncthreads();
  unsigned short* dstn = B2s + (size_t)n * 36864;
  for (int i = t; i < 4608; i += 256) {
    int e0 = i * 8;
    int fi = e0 >> 9, ll = (e0 & 511) >> 3;
    int kb = (fi % 12) * 32 + (ll >> 4) * 8;
    uint4 w = *(const uint4*)(B2 + e0);
    const unsigned* wu = (const unsigned*)&w;
    uint4 o;
    unsigned* ou = (unsigned*)&o;
#pragma unroll
    for (int h = 0; h < 4; h++) {
      float v0 = bf2f((unsigned short)(wu[h] & 0xffffu)) * cf[kb + h * 2];
      float v1 = bf2f((unsigned short)(wu[h] >> 16)) * cf[kb + h * 2 + 1];
      ou[h] = (unsigned)f2bf(v0) | ((unsigned)f2bf(v1) << 16);
    }
    *(uint4*)(dstn + e0) = o;
  }
}

// ---------------- K4: GEMM2 (M x 96 x 384) + residual -------------------
__global__ __launch_bounds__(256) void k4_gemm2(
    const unsigned short* __restrict__ y1f, const unsigned short* __restrict__ B2s,
    const float* __restrict__ b2p, const float* __restrict__ x,
    float* __restrict__ out) {
  __shared__ float zt[96][68];
  const int t  = threadIdx.x;
  const int wv = t >> 6, l = t & 63;
  const int lg = l >> 4, lr = l & 15;
  const int bid = blockIdx.x;
  const int n = bid / 49;
  const int tile = bid - n * 49;
  const int tr = tile / 7, tc = tile - tr * 7;
  const unsigned short* Bn = B2s + (size_t)n * 36864;

  bf16x8_t af[12];
  const unsigned short* ap = y1f + ((size_t)(bid * 4 + wv) * 12) * 512 + l * 8;
#pragma unroll
  for (int kt = 0; kt < 12; kt++)
    af[kt] = *(const bf16x8_t*)(ap + kt * 512);

  f32x4_t acc[6];
#pragma unroll
  for (int i = 0; i < 6; i++) acc[i] = (f32x4_t){0.f, 0.f, 0.f, 0.f};
#pragma unroll
  for (int kt = 0; kt < 12; kt++) {
#pragma unroll
    for (int nt = 0; nt < 6; nt++) {
      bf16x8_t b = *(const bf16x8_t*)(Bn + ((size_t)(nt * 12 + kt) * 64 + l) * 8);
      acc[nt] = __builtin_amdgcn_mfma_f32_16x16x32_bf16(af[kt], b, acc[nt], 0, 0, 0);
    }
  }
#pragma unroll
  for (int nt = 0; nt < 6; nt++) {
    int c = nt * 16 + lr;
#pragma unroll
    for (int r = 0; r < 4; r++)
      zt[c][wv * 16 + lg * 4 + r] = acc[nt][r];
  }
  __syncthreads();
#pragma unroll
  for (int it = 0; it < 6; it++) {
    int id = t + it * 256;  // 1536 = 96 c * 16 quads
    int c = id >> 4, q = id & 15;
    int row = q >> 1, jq = (q & 1) * 4;
    float4 z = *(const float4*)&zt[c][row * 8 + jq];
    size_t base = ((size_t)(n * 96 + c)) * HW + (size_t)(tr * 8 + row) * 56 + tc * 8 + jq;
    float4 xv = *(const float4*)(x + base);
    float bp = b2p[c];
    float4 o;
    o.x = xv.x + z.x + bp;
    o.y = xv.y + z.y + bp;
    o.z = xv.z + z.z + bp;
    o.w = xv.w + z.w + bp;
    *(float4*)(out + base) = o;
  }
}

// ---------------- launch -----------------------------------------------
extern "C" void kernel_launch(void* const* d_in, const int* in_sizes, int n_in,
                              void* d_out, int out_size, void* d_ws, size_t ws_size,
                              hipStream_t stream) {
  const float* x    = (const float*)d_in[0];
  const float* dww  = (const float*)d_in[1];
  const float* dwb  = (const float*)d_in[2];
  const float* lng  = (const float*)d_in[3];
  const float* lnb  = (const float*)d_in[4];
  const float* w1   = (const float*)d_in[5];
  const float* b1   = (const float*)d_in[6];
  const float* grng = (const float*)d_in[7];
  const float* grnb = (const float*)d_in[8];
  const float* w2   = (const float*)d_in[9];
  const float* b2   = (const float*)d_in[10];
  float* out = (float*)d_out;

  char* ws = (char*)d_ws;
  size_t off = 0;
  auto alloc = [&](size_t bytes) {
    char* p = ws + off;
    off += (bytes + 255) & ~(size_t)255;
    return p;
  };
  unsigned short* y1f  = (unsigned short*)alloc((size_t)M_TOT * 384 * 2);
  unsigned short* B2s  = (unsigned short*)alloc((size_t)64 * 36864 * 2);
  unsigned short* B1sw = (unsigned short*)alloc((size_t)384 * 96 * 2);
  unsigned short* B2sw = (unsigned short*)alloc((size_t)96 * 384 * 2);
  unsigned short* wswz = (unsigned short*)alloc((size_t)96 * 56 * 2);
  float* gx2  = (float*)alloc((size_t)64 * 384 * 4);
  float* b2p  = (float*)alloc((size_t)96 * 4);
  if (off > ws_size) return;

  hipMemsetAsync(gx2, 0, 64 * 384 * 4, stream);
  k0_swz<<<18, 256, 0, stream>>>(w1, B1sw, 384, 96);
  k0_swz<<<18, 256, 0, stream>>>(w2, B2sw, 96, 384);
  k0_b2p<<<1, 128, 0, stream>>>(w2, grnb, b2, b2p);
  k0w<<<21, 256, 0, stream>>>(dww, wswz);
  k12f<<<3136, 256, 0, stream>>>(x, wswz, dwb, lng, lnb, B1sw, b1, y1f, gx2);
  k3_coefB<<<64, 256, 0, stream>>>(gx2, grng, B2sw, B2s);
  k4_gemm2<<<3136, 256, 0, stream>>>(y1f, B2s, b2p, x, out);
}

// Round 13
// 237.545 us; speedup vs baseline: 1.1694x; 1.1342x over previous
//
#include <hip/hip_runtime.h>
#include <hip/hip_bf16.h>
#include <math.h>

#define HW   3136
#define NIMG 64
#define M_TOT (NIMG * HW)   // 200704

typedef __attribute__((ext_vector_type(8))) short bf16x8_t;
typedef __attribute__((ext_vector_type(4))) float f32x4_t;

__device__ __forceinline__ unsigned short f2bf(float f) {
  union { float f; unsigned u; } v; v.f = f;
  unsigned r = v.u + 0x7FFFu + ((v.u >> 16) & 1u);
  return (unsigned short)(r >> 16);
}
__device__ __forceinline__ float bf2f(unsigned short h) {
  union { unsigned u; float f; } v; v.u = ((unsigned)h) << 16;
  return v.f;
}

// ---------------- K0: swizzle weight [N][K] into MFMA B-fragment order ----
__global__ void k0_swz(const float* __restrict__ wsrc, unsigned short* __restrict__ bsw,
                       int N, int K) {
  int idx = blockIdx.x * 256 + threadIdx.x;
  int total = (N / 16) * (K / 32) * 64;
  if (idx >= total) return;
  int l  = idx & 63;
  int fi = idx >> 6;
  int KT = K / 32;
  int nt = fi / KT, kt = fi - nt * KT;
  int nn = nt * 16 + (l & 15);
  int kb = kt * 32 + (l >> 4) * 8;
  const float* src = wsrc + (size_t)nn * K + kb;
  unsigned short* dst = bsw + (size_t)idx * 8;
#pragma unroll
  for (int j = 0; j < 8; j++) dst[j] = f2bf(src[j]);
}

// ---------------- K0c: fold GRN beta through w2 into bias ---------------
__global__ void k0_b2p(const float* __restrict__ w2, const float* __restrict__ grnb,
                       const float* __restrict__ b2, float* __restrict__ b2p) {
  int c = blockIdx.x * blockDim.x + threadIdx.x;
  if (c >= 96) return;
  float s = b2[c];
  const float* wr = w2 + (size_t)c * 384;
  for (int f = 0; f < 384; f++) s += grnb[f] * wr[f];
  b2p[c] = s;
}

// ---------------- K0w: dwconv weights -> bf16, rows padded to 8 ---------
__global__ void k0w(const float* __restrict__ dww, unsigned short* __restrict__ wswz) {
  int i = blockIdx.x * 256 + threadIdx.x;   // over 96*56
  if (i >= 96 * 56) return;
  int ch = i / 56, rem = i - ch * 56, dy = rem >> 3, dx = rem & 7;
  wswz[i] = (dx < 7) ? f2bf(dww[ch * 49 + dy * 7 + dx]) : (unsigned short)0;
}

// ===== K12f: FUSED dwconv + transpose + LN + GEMM1 + GELU + gx2 =========
// Block = one 8x8 pixel tile of one image (grid 64*49). 256 threads.
// r13: y1 emitted as fp8 e4m3 (halves y1 traffic; cvt_pk epilogue);
// fully-interior tiles take branch-free float4 staging.
__global__ __launch_bounds__(256, 3) void k12f(
    const float* __restrict__ x, const unsigned short* __restrict__ wswz,
    const float* __restrict__ dwb, const float* __restrict__ lng,
    const float* __restrict__ lnb, const unsigned short* __restrict__ B1,
    const float* __restrict__ b1, unsigned char* __restrict__ y1f8,
    float* __restrict__ gx2) {
  __shared__ char smem[28928];
  float* lnp = (float*)smem;                                    // 768 B
  unsigned short* xsh = (unsigned short*)(smem + 768);          // [32] ch-stride 232 us, 14848 B
  unsigned short (*ts)[104] = (unsigned short(*)[104])(smem + 15616);  // 13312 B
  unsigned char* ytB = (unsigned char*)(smem + 768);            // [64][200] fp8, aliases xsh/ts

  const int t = threadIdx.x;
  const int bid = blockIdx.x;
  const int n = bid / 49;
  const int tile = bid - n * 49;
  const int tr = tile / 7, tc = tile - tr * 7;
  const int h0 = tr * 8, w0 = tc * 8;

  if (t < 192) lnp[t] = (t < 96) ? lng[t] : lnb[t - 96];

  // ---- conv: 3 chunks of 32 channels ----
  const int cch = t & 31, crow = t >> 5;
  const bool colInt = (tc >= 1) && (tc <= 5);
  const bool rowInt = (tr >= 1) && (tr <= 5);
  for (int cc = 0; cc < 3; cc++) {
    const int c0 = cc * 32;
    if (cc) __syncthreads();
#pragma unroll
    for (int k = 0; k < 7; k++) {
      int i = t + k * 256;                 // < 1792
      int cq = i & 3;
      int rc = i >> 2;
      int r = rc % 14, ch = rc / 14;
      int h = h0 + r - 3;
      int wb = w0 + cq * 4 - 3;
      const float* xb = x + (size_t)(n * 96 + c0 + ch) * HW + h * 56 + wb;
      float4 v;
      if (rowInt && colInt) {
        v = *(const float4*)xb;            // fully interior: branch-free
      } else {
        v = make_float4(0.f, 0.f, 0.f, 0.f);
        if ((unsigned)h < 56u) {
          if (colInt) {
            v = *(const float4*)xb;
          } else {
            if ((unsigned)(wb + 0) < 56u) v.x = xb[0];
            if ((unsigned)(wb + 1) < 56u) v.y = xb[1];
            if ((unsigned)(wb + 2) < 56u) v.z = xb[2];
            if ((unsigned)(wb + 3) < 56u) v.w = xb[3];
          }
        }
      }
      uint2 u;
      u.x = (unsigned)f2bf(v.x) | ((unsigned)f2bf(v.y) << 16);
      u.y = (unsigned)f2bf(v.z) | ((unsigned)f2bf(v.w) << 16);
      *(uint2*)&xsh[ch * 232 + r * 16 + cq * 4] = u;
    }
    bf16x8_t wv[7];
#pragma unroll
    for (int dy = 0; dy < 7; dy++)
      wv[dy] = *(const bf16x8_t*)&wswz[(size_t)(c0 + cch) * 56 + dy * 8];
    const float bias = dwb[c0 + cch];
    __syncthreads();
    float acc[8];
#pragma unroll
    for (int j = 0; j < 8; j++) acc[j] = bias;
#pragma unroll
    for (int dy = 0; dy < 7; dy++) {
      float wf[7];
#pragma unroll
      for (int dx = 0; dx < 7; dx++) wf[dx] = bf2f((unsigned short)wv[dy][dx]);
      const unsigned short* xr = &xsh[cch * 232 + (crow + dy) * 16];
      bf16x8_t x0 = *(const bf16x8_t*)xr;
      bf16x8_t x1 = *(const bf16x8_t*)(xr + 8);
      float r16[14];
#pragma unroll
      for (int k = 0; k < 8; k++) r16[k] = bf2f((unsigned short)x0[k]);
#pragma unroll
      for (int k = 0; k < 6; k++) r16[8 + k] = bf2f((unsigned short)x1[k]);
#pragma unroll
      for (int j = 0; j < 8; j++)
#pragma unroll
        for (int dx = 0; dx < 7; dx++)
          acc[j] = fmaf(wf[dx], r16[j + dx], acc[j]);
    }
#pragma unroll
    for (int j = 0; j < 8; j++)
      ts[crow * 8 + j][c0 + cch] = f2bf(acc[j]);
  }
  __syncthreads();

  // ---- LayerNorm: 4 threads per pixel ----
  {
    const int px = t >> 2, q = t & 3;
    unsigned vu[12];
    float s = 0.f, ss = 0.f;
#pragma unroll
    for (int j = 0; j < 12; j++) {
      vu[j] = *(const unsigned*)&ts[px][q * 24 + j * 2];
      float v0 = bf2f((unsigned short)(vu[j] & 0xffffu));
      float v1 = bf2f((unsigned short)(vu[j] >> 16));
      s += v0 + v1; ss += v0 * v0 + v1 * v1;
    }
    s  += __shfl_xor(s, 1);  s  += __shfl_xor(s, 2);
    ss += __shfl_xor(ss, 1); ss += __shfl_xor(ss, 2);
    float mu  = s * (1.f / 96.f);
    float var = ss * (1.f / 96.f) - mu * mu;
    float rs  = rsqrtf(var + 1e-6f);
#pragma unroll
    for (int j = 0; j < 12; j++) {
      int ch = q * 24 + j * 2;
      float v0 = bf2f((unsigned short)(vu[j] & 0xffffu));
      float v1 = bf2f((unsigned short)(vu[j] >> 16));
      float o0 = (v0 - mu) * rs * lnp[ch] + lnp[96 + ch];
      float o1 = (v1 - mu) * rs * lnp[ch + 1] + lnp[96 + ch + 1];
      *(unsigned*)&ts[px][ch] = (unsigned)f2bf(o0) | ((unsigned)f2bf(o1) << 16);
    }
  }
  __syncthreads();
  // ---- A fragments from ts ----
  const int wv_ = t >> 6, l = t & 63;
  const int lg = l >> 4, lr = l & 15;
  bf16x8_t af[4][3];
#pragma unroll
  for (int mt = 0; mt < 4; mt++)
#pragma unroll
    for (int kt = 0; kt < 3; kt++)
      af[mt][kt] = *(const bf16x8_t*)&ts[mt * 16 + lr][kt * 32 + lg * 8];
  __syncthreads();   // ts dies; ytB (aliased) may be written

  // ---- GEMM1 + GELU + gx2, two half-feature passes; y1 -> fp8 ----
  for (int half = 0; half < 2; half++) {
    for (int i = 0; i < 3; i++) {
      const int ntl = wv_ * 3 + i;
      const int nt  = half * 12 + ntl;
      bf16x8_t bf[3];
#pragma unroll
      for (int kt = 0; kt < 3; kt++)
        bf[kt] = *(const bf16x8_t*)(B1 + ((size_t)(nt * 3 + kt) * 64 + l) * 8);
      f32x4_t acc[4];
#pragma unroll
      for (int mt = 0; mt < 4; mt++) {
        f32x4_t a = {0.f, 0.f, 0.f, 0.f};
#pragma unroll
        for (int kt = 0; kt < 3; kt++)
          a = __builtin_amdgcn_mfma_f32_16x16x32_bf16(af[mt][kt], bf[kt], a, 0, 0, 0);
        acc[mt] = a;
      }
      const int f0 = nt * 16, fl0 = ntl * 16;
      float bias = b1[f0 + lr];
      float s2 = 0.f;
#pragma unroll
      for (int mt = 0; mt < 4; mt++) {
#pragma unroll
        for (int r = 0; r < 4; r++) {
          float v = acc[mt][r] + bias;
          float sq = v * v;
          float pe = fmaf(sq, -0.10295294f, -2.3021183f);
          float e  = __builtin_amdgcn_exp2f(v * pe);
          float g  = v * __builtin_amdgcn_rcpf(1.f + e);
          s2 += g * g;
          unsigned p8 = (unsigned)__builtin_amdgcn_cvt_pk_fp8_f32(g, g, 0, false);
          ytB[(mt * 16 + lg * 4 + r) * 200 + fl0 + lr] = (unsigned char)p8;
        }
      }
      s2 += __shfl_xor(s2, 16);
      s2 += __shfl_xor(s2, 32);
      if (l < 16) atomicAdd(gx2 + n * 384 + f0 + l, s2);
    }
    __syncthreads();
    // frag-major fp8 readout of this half (b64 LDS reads, uint2 stores)
#pragma unroll
    for (int it = 0; it < 6; it++) {
      int id = t + it * 256;               // 1536 = 4 mt * 6 ktl * 64 ll
      int mt = id / 384, ktl = (id >> 6) % 6, ll = id & 63;
      unsigned long long d =
        *(const unsigned long long*)&ytB[(mt * 16 + (ll & 15)) * 200 + ktl * 32 + (ll >> 4) * 8];
      *(unsigned long long*)(y1f8 +
        (((size_t)(bid * 4 + mt) * 12 + half * 6 + ktl) * 64 + ll) * 8) = d;
    }
    __syncthreads();
  }
}

// -------- K3: GRN coefficients + per-image scaled B2 fragments (fp8) ----
__global__ __launch_bounds__(256) void k3_coefB(
    const float* __restrict__ gx2, const float* __restrict__ grng,
    const unsigned short* __restrict__ B2, unsigned char* __restrict__ B2s8) {
  __shared__ float red[256];
  __shared__ float cf[384];
  const int n = blockIdx.x, t = threadIdx.x;
  float s = 0.f;
  for (int f = t; f < 384; f += 256) {
    float g = sqrtf(gx2[n * 384 + f]);
    cf[f] = g; s += g;
  }
  red[t] = s; __syncthreads();
  for (int o = 128; o > 0; o >>= 1) {
    if (t < o) red[t] += red[t + o];
    __syncthreads();
  }
  float inv = 1.f / (red[0] * (1.f / 384.f) + 1e-6f);
  for (int f = t; f < 384; f += 256)
    cf[f] = 1.f + grng[f] * cf[f] * inv;
  __syncthreads();
  unsigned char* dstn = B2s8 + (size_t)n * 36864;
  for (int i = t; i < 4608; i += 256) {        // 4608 groups of 8 elems
    int e0 = i * 8;
    int fi = e0 >> 9, ll = (e0 & 511) >> 3;
    int kb = (fi % 12) * 32 + (ll >> 4) * 8;
    uint4 w = *(const uint4*)(B2 + e0);
    const unsigned* wu = (const unsigned*)&w;
    float vv[8];
#pragma unroll
    for (int h = 0; h < 4; h++) {
      vv[h * 2 + 0] = bf2f((unsigned short)(wu[h] & 0xffffu)) * cf[kb + h * 2];
      vv[h * 2 + 1] = bf2f((unsigned short)(wu[h] >> 16)) * cf[kb + h * 2 + 1];
    }
    unsigned p0 = (unsigned)__builtin_amdgcn_cvt_pk_fp8_f32(vv[0], vv[1], 0, false);
    p0 = (unsigned)__builtin_amdgcn_cvt_pk_fp8_f32(vv[2], vv[3], p0, true);
    unsigned p1 = (unsigned)__builtin_amdgcn_cvt_pk_fp8_f32(vv[4], vv[5], 0, false);
    p1 = (unsigned)__builtin_amdgcn_cvt_pk_fp8_f32(vv[6], vv[7], p1, true);
    uint2 o; o.x = p0; o.y = p1;
    *(uint2*)(dstn + e0) = o;
  }
}

// ---------------- K4: fp8 GEMM2 (M x 96 x 384) + residual ---------------
__global__ __launch_bounds__(256) void k4_gemm2(
    const unsigned char* __restrict__ y1f8, const unsigned char* __restrict__ B2s8,
    const float* __restrict__ b2p, const float* __restrict__ x,
    float* __restrict__ out) {
  __shared__ float zt[96][68];
  const int t  = threadIdx.x;
  const int wv = t >> 6, l = t & 63;
  const int lg = l >> 4, lr = l & 15;
  const int bid = blockIdx.x;
  const int n = bid / 49;
  const int tile = bid - n * 49;
  const int tr = tile / 7, tc = tile - tr * 7;
  const unsigned char* Bn = B2s8 + (size_t)n * 36864;

  long af[12];
  const unsigned char* ap = y1f8 + ((size_t)(bid * 4 + wv) * 12) * 512 + l * 8;
#pragma unroll
  for (int kt = 0; kt < 12; kt++)
    af[kt] = *(const long*)(ap + kt * 512);

  f32x4_t acc[6];
#pragma unroll
  for (int i = 0; i < 6; i++) acc[i] = (f32x4_t){0.f, 0.f, 0.f, 0.f};
#pragma unroll
  for (int kt = 0; kt < 12; kt++) {
#pragma unroll
    for (int nt = 0; nt < 6; nt++) {
      long b = *(const long*)(Bn + ((size_t)(nt * 12 + kt) * 64 + l) * 8);
      acc[nt] = __builtin_amdgcn_mfma_f32_16x16x32_fp8_fp8(af[kt], b, acc[nt], 0, 0, 0);
    }
  }
#pragma unroll
  for (int nt = 0; nt < 6; nt++) {
    int c = nt * 16 + lr;
#pragma unroll
    for (int r = 0; r < 4; r++)
      zt[c][wv * 16 + lg * 4 + r] = acc[nt][r];
  }
  __syncthreads();
#pragma unroll
  for (int it = 0; it < 6; it++) {
    int id = t + it * 256;  // 1536 = 96 c * 16 quads
    int c = id >> 4, q = id & 15;
    int row = q >> 1, jq = (q & 1) * 4;
    float4 z = *(const float4*)&zt[c][row * 8 + jq];
    size_t base = ((size_t)(n * 96 + c)) * HW + (size_t)(tr * 8 + row) * 56 + tc * 8 + jq;
    float4 xv = *(const float4*)(x + base);
    float bp = b2p[c];
    float4 o;
    o.x = xv.x + z.x + bp;
    o.y = xv.y + z.y + bp;
    o.z = xv.z + z.z + bp;
    o.w = xv.w + z.w + bp;
    *(float4*)(out + base) = o;
  }
}

// ---------------- launch -----------------------------------------------
extern "C" void kernel_launch(void* const* d_in, const int* in_sizes, int n_in,
                              void* d_out, int out_size, void* d_ws, size_t ws_size,
                              hipStream_t stream) {
  const float* x    = (const float*)d_in[0];
  const float* dww  = (const float*)d_in[1];
  const float* dwb  = (const float*)d_in[2];
  const float* lng  = (const float*)d_in[3];
  const float* lnb  = (const float*)d_in[4];
  const float* w1   = (const float*)d_in[5];
  const float* b1   = (const float*)d_in[6];
  const float* grng = (const float*)d_in[7];
  const float* grnb = (const float*)d_in[8];
  const float* w2   = (const float*)d_in[9];
  const float* b2   = (const float*)d_in[10];
  float* out = (float*)d_out;

  char* ws = (char*)d_ws;
  size_t off = 0;
  auto alloc = [&](size_t bytes) {
    char* p = ws + off;
    off += (bytes + 255) & ~(size_t)255;
    return p;
  };
  unsigned char*  y1f8 = (unsigned char*)alloc((size_t)M_TOT * 384);      // fp8
  unsigned char*  B2s8 = (unsigned char*)alloc((size_t)64 * 36864);       // fp8
  unsigned short* B1sw = (unsigned short*)alloc((size_t)384 * 96 * 2);
  unsigned short* B2sw = (unsigned short*)alloc((size_t)96 * 384 * 2);
  unsigned short* wswz = (unsigned short*)alloc((size_t)96 * 56 * 2);
  float* gx2  = (float*)alloc((size_t)64 * 384 * 4);
  float* b2p  = (float*)alloc((size_t)96 * 4);
  if (off > ws_size) return;

  hipMemsetAsync(gx2, 0, 64 * 384 * 4, stream);
  k0_swz<<<18, 256, 0, stream>>>(w1, B1sw, 384, 96);
  k0_swz<<<18, 256, 0, stream>>>(w2, B2sw, 96, 384);
  k0_b2p<<<1, 128, 0, stream>>>(w2, grnb, b2, b2p);
  k0w<<<21, 256, 0, stream>>>(dww, wswz);
  k12f<<<3136, 256, 0, stream>>>(x, wswz, dwb, lng, lnb, B1sw, b1, y1f8, gx2);
  k3_coefB<<<64, 256, 0, stream>>>(gx2, grng, B2sw, B2s8);
  k4_gemm2<<<3136, 256, 0, stream>>>(y1f8, B2s8, b2p, x, out);
}